// Round 6
// baseline (542.722 us; speedup 1.0000x reference)
//
#include <hip/hip_runtime.h>

#define LS 1323000
#define NB 98
#define MM 123000
#define N2 3000            // MM / 41
#define BATCH 2
#define NROWS_T (NB*BATCH)
#define TWO_PI 6.28318530717958647692f

// Bb bf16 layout per row: [kb<188][q<96][kl<16], ushort units
#define KBN 188
#define QN  96
#define SROW (KBN*QN*16)       // 288768 ushorts = 577536 B per row
#define QP  104                // padded q stride in LDS (bank-conflict-free)

typedef __attribute__((ext_vector_type(8))) short short8;
typedef __attribute__((ext_vector_type(4))) float f32x4;

__device__ __forceinline__ float2 cmul(float2 a, float2 b){
  return make_float2(a.x*b.x - a.y*b.y, a.x*b.y + a.y*b.x);
}
__device__ __forceinline__ unsigned short f2bf(float f){
  unsigned int u = __float_as_uint(f);
  unsigned int r = (u + 0x7FFFu + ((u >> 16) & 1u)) >> 16;
  return (unsigned short)r;
}

// Small DFT of size R with sign S (+1 inverse, -1 forward), in-place on v[R].
template<int R,int S>
__device__ __forceinline__ void butterfly(float2* v){
  if constexpr (R==2){
    float2 a=v[0], b=v[1];
    v[0]=make_float2(a.x+b.x, a.y+b.y);
    v[1]=make_float2(a.x-b.x, a.y-b.y);
  } else if constexpr (R==4){
    float2 t0=make_float2(v[0].x+v[2].x, v[0].y+v[2].y);
    float2 t1=make_float2(v[0].x-v[2].x, v[0].y-v[2].y);
    float2 t2=make_float2(v[1].x+v[3].x, v[1].y+v[3].y);
    float2 t3=make_float2(v[1].x-v[3].x, v[1].y-v[3].y);
    v[0]=make_float2(t0.x+t2.x, t0.y+t2.y);
    v[2]=make_float2(t0.x-t2.x, t0.y-t2.y);
    v[1]=make_float2(t1.x - (float)S*t3.y, t1.y + (float)S*t3.x);
    v[3]=make_float2(t1.x + (float)S*t3.y, t1.y - (float)S*t3.x);
  } else if constexpr (R==8){
    float2 e[4]={v[0],v[2],v[4],v[6]};
    float2 o[4]={v[1],v[3],v[5],v[7]};
    butterfly<4,S>(e);
    butterfly<4,S>(o);
    const float h = 0.70710678118654752440f;
    float2 w1=make_float2(h, (float)S*h);
    float2 w2=make_float2(0.f, (float)S);
    float2 w3=make_float2(-h, (float)S*h);
    float2 o1=cmul(o[1],w1), o2=cmul(o[2],w2), o3=cmul(o[3],w3);
    v[0]=make_float2(e[0].x+o[0].x, e[0].y+o[0].y);
    v[4]=make_float2(e[0].x-o[0].x, e[0].y-o[0].y);
    v[1]=make_float2(e[1].x+o1.x, e[1].y+o1.y);
    v[5]=make_float2(e[1].x-o1.x, e[1].y-o1.y);
    v[2]=make_float2(e[2].x+o2.x, e[2].y+o2.y);
    v[6]=make_float2(e[2].x-o2.x, e[2].y-o2.y);
    v[3]=make_float2(e[3].x+o3.x, e[3].y+o3.y);
    v[7]=make_float2(e[3].x-o3.x, e[7-4].y-o3.y);
    v[7]=make_float2(e[3].x-o3.x, e[3].y-o3.y);
  } else {
    float2 x[R];
    #pragma unroll
    for(int k=0;k<R;k++){
      float2 acc=v[0];
      #pragma unroll
      for(int n=1;n<R;n++){
        const int p=(k*n)%R;
        float ang = (float)S * (TWO_PI/(float)R) * (float)p;
        float sn,cs; __sincosf(ang,&sn,&cs);
        acc.x += v[n].x*cs - v[n].y*sn;
        acc.y += v[n].x*sn + v[n].y*cs;
      }
      x[k]=acc;
    }
    #pragma unroll
    for(int k=0;k<R;k++) v[k]=x[k];
  }
}

// One global Stockham pass (forward only).
template<int R,int S>
__global__ void __launch_bounds__(256)
fft_pass(const float2* __restrict__ in, float2* __restrict__ out,
         int N, int Ns, int nrows){
  const int T = N / R;
  long long gid = (long long)blockIdx.x*blockDim.x + threadIdx.x;
  if (gid >= (long long)T*nrows) return;
  int row = (int)(gid / T);
  int j   = (int)(gid - (long long)row*T);
  const float2* x = in  + (size_t)row*N;
  float2*       y = out + (size_t)row*N;
  int t = j % Ns;
  float u = (float)t / (float)(Ns*R);
  float ang = (float)S * TWO_PI * u;
  float sn,cs; __sincosf(ang,&sn,&cs);
  float2 w1=make_float2(cs,sn);
  float2 wr=make_float2(1.f,0.f);
  float2 v[R];
  #pragma unroll
  for(int r=0;r<R;r++){
    float2 a = x[j + r*T];
    v[r] = cmul(a, wr);
    wr = cmul(wr, w1);
  }
  butterfly<R,S>(v);
  int d = (j/Ns)*(Ns*R) + t;
  #pragma unroll
  for(int r=0;r<R;r++) y[d + r*Ns] = v[r];
}

// First forward pass: radix-8, Ns=1 (no twiddles), reads real input directly.
__global__ void __launch_bounds__(256)
fft_r2c8(const float* __restrict__ s, float2* __restrict__ y){
  const int T = LS/8;
  long long gid = (long long)blockIdx.x*blockDim.x + threadIdx.x;
  if (gid >= (long long)T*BATCH) return;
  int row = (int)(gid / T);
  int j   = (int)(gid - (long long)row*T);
  const float* x = s + (size_t)row*LS;
  float2*      yr = y + (size_t)row*LS;
  float2 v[8];
  #pragma unroll
  for(int r=0;r<8;r++) v[r] = make_float2(x[j + r*T], 0.f);
  butterfly<8,-1>(v);
  int d = 8*j;
  #pragma unroll
  for(int r=0;r<8;r++) yr[d + r] = v[r];
}

// ---- parallel rowspan: head-max / tail-min of nonzero gw per row ----
__global__ void span_init(int* __restrict__ spanA, int* __restrict__ spanB){
  int j = blockIdx.x*blockDim.x + threadIdx.x;
  if (j < NB){ spanA[j] = 0; spanB[j] = MM; }
}

#define SPAN_SLICE 4096
__global__ void __launch_bounds__(256)
rowspan_par(const float* __restrict__ gw, int* __restrict__ spanA,
            int* __restrict__ spanB){
  const int j  = blockIdx.x;
  const int lo = blockIdx.y * SPAN_SLICE;
  const int end = min(lo + SPAN_SLICE, MM);
  const float* g = gw + (size_t)j*MM;
  const int tid = threadIdx.x;
  int mA = -1, mB = MM;
  for (int m = lo + tid*4; m < end; m += 256*4){
    float4 v = *(const float4*)(g + m);
    #pragma unroll
    for (int t = 0; t < 4; t++){
      float f = ((const float*)&v)[t];
      int m2 = m + t;
      if (f != 0.f){
        if (m2 < 61500){ if (m2 > mA) mA = m2; }
        else           { if (m2 < mB) mB = m2; }
      }
    }
  }
  __shared__ int sA[256], sB[256];
  sA[tid]=mA; sB[tid]=mB; __syncthreads();
  for (int s=128; s>0; s>>=1){
    if (tid<s){ sA[tid]=max(sA[tid],sA[tid+s]); sB[tid]=min(sB[tid],sB[tid+s]); }
    __syncthreads();
  }
  if (tid==0){
    if (sA[0] >= 0) atomicMax(&spanA[j], sA[0]+1);
    if (sB[0] < MM) atomicMin(&spanB[j], sB[0]);
  }
}

// Precompute the 96x96 (padded to [96][QP]) bf16 real-form W matrix.
__global__ void __launch_bounds__(256)
a_prep(unsigned short* __restrict__ A96){
  int i = blockIdx.x*blockDim.x + threadIdx.x;
  if (i >= 96*QP) return;
  int R = i / QP, q = i - R*QP;
  float val = 0.f;
  if (R < 82 && q < 82){
    int k2 = R >> 1, c = R & 1, n2 = q >> 1, cp = q & 1;
    int p = (k2*n2) % 41;
    float ang = (float)p * (TWO_PI/41.f);
    float sn, cs; __sincosf(ang, &sn, &cs);
    val = c ? (cp ? cs : sn) : (cp ? -sn : cs);
  }
  A96[i] = f2bf(val);
}

// ---- pack_gather: coalesced gather + 41-comb transpose into T[row][n2][i] ----
// T lives in d_out (dead storage until inv_s2 overwrites it). Only the
// span-pruned head/tail elements are written (all inv_s1 will read).
#define PTILE 1681   // 41*41
__global__ void __launch_bounds__(256)
pack_gather(const float2* __restrict__ ft, const int* __restrict__ idx,
            const float* __restrict__ gw, const int* __restrict__ spanA,
            const int* __restrict__ spanB, float2* __restrict__ T, int row0){
  const int row  = row0 + blockIdx.y;
  const int jrow = row % NB;
  const int b    = row / NB;
  const int spA = spanA[jrow], spB = spanB[jrow];
  const int base = blockIdx.x * PTILE;
  const int end  = min(base + PTILE, MM);
  if (!(base < spA || end > spB)) return;     // tile entirely in zero middle
  __shared__ float2 tile[PTILE];              // 13448 B
  const int cnt = end - base;
  const int*   idxr = idx + (size_t)jrow*MM;
  const float* gwr  = gw  + (size_t)jrow*MM;
  const float2* ftb = ft  + (size_t)b*LS;
  for (int l = threadIdx.x; l < cnt; l += 256){
    int n = base + l;
    float g = gwr[n] * (1.0f/(float)MM);
    float2 f = ftb[idxr[n]];
    tile[l] = make_float2(f.x*g, f.y*g);
  }
  __syncthreads();
  float2* Trow = T + (size_t)blockIdx.y*MM;
  const int bm = base % 41;
  for (int l2 = threadIdx.x; l2 < PTILE; l2 += 256){
    int n2 = l2 / 41, w = l2 - 41*n2;
    int l0 = n2 - bm; if (l0 < 0) l0 += 41;
    int l = l0 + 41*w;
    if (l < cnt){
      int n = base + l;
      if (n < spA || n >= spB){
        int ig = n / 41;
        Trow[(size_t)n2*N2 + ig] = tile[l];
      }
    }
  }
}

// LDS Stockham stage for the 3000-pt inverse FFT.
template<int R, int Ns>
__device__ __forceinline__ void lds_stage(const float2* src, float2* dst, int tid){
  const int T = N2 / R;
  for (int j = tid; j < T; j += 256){
    int t = j % Ns;
    float2 w1;
    if constexpr (Ns == 1) w1 = make_float2(1.f, 0.f);
    else {
      float ang = TWO_PI * (float)t / (float)(Ns*R);
      float sn, cs; __sincosf(ang, &sn, &cs);
      w1 = make_float2(cs, sn);
    }
    float2 wr = make_float2(1.f, 0.f);
    float2 v[R];
    #pragma unroll
    for (int r = 0; r < R; r++){ v[r] = cmul(src[j + r*T], wr); wr = cmul(wr, w1); }
    butterfly<R,1>(v);
    int d = (j/Ns)*(Ns*R) + t;
    #pragma unroll
    for (int r = 0; r < R; r++) dst[d + r*Ns] = v[r];
  }
}

// Inverse stage 1: per (row, n2): read packed comb (contiguous) -> 3000-pt
// LDS FFT -> twiddle -> bf16 store into MFMA-tiled layout.
__global__ void __launch_bounds__(256)
inv_s1(const float2* __restrict__ T, const int* __restrict__ spanA,
       const int* __restrict__ spanB,
       unsigned short* __restrict__ Bb, int row0){
  __shared__ float2 u0[N2];  // 24 KB
  __shared__ float2 u1[N2];  // 24 KB
  const int n2  = blockIdx.x;            // 0..40
  const int row = row0 + blockIdx.y;
  const int jrow = row % NB;
  const int tid = threadIdx.x;
  const int spA = spanA[jrow], spB = spanB[jrow];
  const int n1A = (spA - n2 + 40) / 41;
  const int n1B = (spB - n2 + 40) / 41;
  const float2* Trow = T + (size_t)blockIdx.y*MM + (size_t)n2*N2;
  for (int i = tid; i < N2; i += 256){
    float2 val = make_float2(0.f, 0.f);
    if (i < n1A || i >= n1B) val = Trow[i];
    u0[i] = val;
  }
  __syncthreads();
  lds_stage<5,1>(u0, u1, tid);   __syncthreads();
  lds_stage<5,5>(u1, u0, tid);   __syncthreads();
  lds_stage<5,25>(u0, u1, tid);  __syncthreads();
  lds_stage<3,125>(u1, u0, tid); __syncthreads();
  lds_stage<8,375>(u0, u1, tid); __syncthreads();
  unsigned short* Brow = Bb + (size_t)blockIdx.y*SROW;
  const int qr = 2*n2, qi = 2*n2+1;
  for (int k1 = tid; k1 < N2; k1 += 256){
    float ang = (float)(n2*k1) * (TWO_PI/(float)MM);  // n2*k1 <= 119960, exact fp32
    float sn, cs; __sincosf(ang, &sn, &cs);
    float2 v = cmul(u1[k1], make_float2(cs, sn));
    int kb = k1 >> 4, kl = k1 & 15;
    size_t base = (size_t)kb*(QN*16) + kl;
    Brow[base + qr*16] = f2bf(v.x);
    Brow[base + qi*16] = f2bf(v.y);
  }
}

// Inverse stage 2 via MFMA: Out[R][k1] = sum_q A96[R][q] * B[q][k1].
__global__ void __launch_bounds__(256)
inv_s2_mfma(const unsigned short* __restrict__ A96,
            const unsigned short* __restrict__ Bb,
            float2* __restrict__ out){
  __shared__ unsigned short Als[96*QP];   // 19968 B
  __shared__ unsigned short Bls[64*QP];   // 13312 B
  const int tid = threadIdx.x;

  {
    const uint4* src = (const uint4*)A96;
    uint4* dst = (uint4*)Als;
    for (int f = tid; f < (96*QP*2)/16; f += 256) dst[f] = src[f];
  }
  {
    const unsigned short* Bt = Bb + (size_t)blockIdx.y*SROW
                                  + (size_t)blockIdx.x*4*(QN*16);
    for (int f = tid; f < 768; f += 256){
      uint4 d = *(const uint4*)(Bt + (size_t)f*8);
      int q   = (f >> 1) % QN;
      int kb  = f / (QN*2);
      int kl0 = (f & 1) * 8;
      if (q >= 82) d = make_uint4(0u,0u,0u,0u);
      const unsigned short* e = (const unsigned short*)&d;
      int rbase = kb*16 + kl0;
      #pragma unroll
      for (int j = 0; j < 8; j++)
        Bls[(rbase + j)*QP + q] = e[j];
    }
  }
  __syncthreads();

  const int w = tid >> 6, l = tid & 63;
  const int g = l >> 4, c = l & 15;

  f32x4 acc[6];
  #pragma unroll
  for (int m = 0; m < 6; m++) acc[m] = (f32x4){0.f,0.f,0.f,0.f};

  short8 b0 = *(const short8*)&Bls[(16*w + c)*QP +  0 + 8*g];
  short8 b1 = *(const short8*)&Bls[(16*w + c)*QP + 32 + 8*g];
  short8 b2 = *(const short8*)&Bls[(16*w + c)*QP + 64 + 8*g];
  #pragma unroll
  for (int m = 0; m < 6; m++){
    short8 a0 = *(const short8*)&Als[(16*m + c)*QP +  0 + 8*g];
    short8 a1 = *(const short8*)&Als[(16*m + c)*QP + 32 + 8*g];
    short8 a2 = *(const short8*)&Als[(16*m + c)*QP + 64 + 8*g];
    acc[m] = __builtin_amdgcn_mfma_f32_16x16x32_bf16(a0, b0, acc[m], 0, 0, 0);
    acc[m] = __builtin_amdgcn_mfma_f32_16x16x32_bf16(a1, b1, acc[m], 0, 0, 0);
    acc[m] = __builtin_amdgcn_mfma_f32_16x16x32_bf16(a2, b2, acc[m], 0, 0, 0);
  }

  float2* orow = out + (size_t)blockIdx.y*MM;
  int k1 = blockIdx.x*64 + 16*w + c;
  if (k1 < N2){
    #pragma unroll
    for (int m = 0; m < 6; m++){
      int R0 = 16*m + 4*g;          // even
      int k2a = R0 >> 1;
      int k2b = k2a + 1;
      if (k2a < 41) orow[(size_t)k2a*N2 + k1] = make_float2(acc[m][0], acc[m][1]);
      if (k2b < 41) orow[(size_t)k2b*N2 + k1] = make_float2(acc[m][2], acc[m][3]);
    }
  }
}

extern "C" void kernel_launch(void* const* d_in, const int* in_sizes, int n_in,
                              void* d_out, int out_size, void* d_ws, size_t ws_size,
                              hipStream_t stream){
  const float* s   = (const float*)d_in[0];
  const int*   idx = (const int*)d_in[1];
  const float* gw  = (const float*)d_in[2];
  float2* out = (float2*)d_out;
  char* ws = (char*)d_ws;

  const size_t FWD_BYTES = 21168128;            // >= BATCH*LS*8, 256-aligned
  float2* bufA = (float2*)ws;
  float2* bufB = (float2*)(ws + FWD_BYTES);
  int* spanA = (int*)(ws + 2*FWD_BYTES);
  int* spanB = (int*)(ws + 2*FWD_BYTES + 512);
  unsigned short* A96 = (unsigned short*)(ws + 2*FWD_BYTES + 1024);
  const size_t A_BYTES = 20480;                 // >= 96*QP*2
  unsigned short* Bbase = (unsigned short*)(ws + 2*FWD_BYTES + 1024 + A_BYTES);

  // 0) W-matrix precompute + span scan (BW-bound, parallel)
  a_prep<<<(96*QP + 255)/256, 256, 0, stream>>>(A96);
  span_init<<<1, 128, 0, stream>>>(spanA, spanB);
  {
    dim3 g(NB, (MM + SPAN_SLICE - 1)/SPAN_SLICE);   // (98, 31)
    rowspan_par<<<g, 256, 0, stream>>>(gw, spanA, spanB);
  }

  // 1) forward FFT: radix-8 r2c + 8 Stockham passes 7,7,5,5,5,3,3,3
  {
    long long tot = (long long)(LS/8)*BATCH;
    int blks = (int)((tot + 255)/256);
    fft_r2c8<<<blks,256,0,stream>>>(s, bufA);
  }
  float2* cur = bufA; float2* nxt = bufB;
  int Ns = 8;
  #define FWD(R) do{                                                         \
    long long tot = (long long)(LS/(R))*BATCH;                               \
    int blks = (int)((tot + 255)/256);                                       \
    fft_pass<R,-1><<<blks,256,0,stream>>>(cur, nxt, LS, Ns, BATCH);          \
    Ns *= (R);                                                               \
    { float2* tmp=cur; cur=nxt; nxt=tmp; }                                   \
  }while(0)
  FWD(7); FWD(7); FWD(5); FWD(5); FWD(5); FWD(3); FWD(3); FWD(3);
  #undef FWD
  // 8 swaps -> ft back in bufA == cur

  // 2) inverse: pack (into d_out as scratch) -> s1 (bf16 B) -> s2 (MFMA)
  const size_t row_bytes = (size_t)SROW * 2;    // 577536 B
  size_t used = 2*FWD_BYTES + 1024 + A_BYTES;
  size_t avail = (ws_size > used) ? (ws_size - used) : 0;
  int max_chunk = (int)(avail / row_bytes);
  if (max_chunk > NROWS_T) max_chunk = NROWS_T;
  if (max_chunk < 1) max_chunk = 1;

  const int ptiles = (MM + PTILE - 1)/PTILE;    // 74
  for (int c0 = 0; c0 < NROWS_T; c0 += max_chunk){
    int cr = NROWS_T - c0; if (cr > max_chunk) cr = max_chunk;
    float2* Tchunk = out + (size_t)c0*MM;
    dim3 g0(ptiles, cr);
    pack_gather<<<g0,256,0,stream>>>(cur, idx, gw, spanA, spanB, Tchunk, c0);
    dim3 g1(41, cr);
    inv_s1<<<g1,256,0,stream>>>(Tchunk, spanA, spanB, Bbase, c0);
    dim3 g2(47, cr);   // 47 * 64 = 3008 >= 3000 k1
    inv_s2_mfma<<<g2,256,0,stream>>>(A96, Bbase, Tchunk);
  }
}

// Round 7
// 515.022 us; speedup vs baseline: 1.0538x; 1.0538x over previous
//
#include <hip/hip_runtime.h>

#define LS 1323000
#define NB 98
#define MM 123000
#define N2 3000            // MM / 41
#define BATCH 2
#define NROWS_T (NB*BATCH)
#define TWO_PI 6.28318530717958647692f

// Bb bf16 layout per row: [kb<188][q<96][kl<16], ushort units
#define KBN 188
#define QN  96
#define SROW (KBN*QN*16)       // 288768 ushorts = 577536 B per row
#define QP  104                // padded q stride in LDS (bank-conflict-free)

// twiddle table offsets (float2 units): stage2 (Ns=5,R=5), stage3 (25,5),
// stage4 (125,3), stage5 (375,8)
#define TBL2_OFF 0
#define TBL3_OFF 20
#define TBL4_OFF 120
#define TBL5_OFF 370
#define TBL_N    2995

typedef __attribute__((ext_vector_type(8))) short short8;
typedef __attribute__((ext_vector_type(4))) float f32x4;

__device__ __forceinline__ float2 cmul(float2 a, float2 b){
  return make_float2(a.x*b.x - a.y*b.y, a.x*b.y + a.y*b.x);
}
__device__ __forceinline__ unsigned short f2bf(float f){
  unsigned int u = __float_as_uint(f);
  unsigned int r = (u + 0x7FFFu + ((u >> 16) & 1u)) >> 16;
  return (unsigned short)r;
}

// Small DFT of size R with sign S (+1 inverse, -1 forward), in-place on v[R].
template<int R,int S>
__device__ __forceinline__ void butterfly(float2* v){
  if constexpr (R==4){
    float2 t0=make_float2(v[0].x+v[2].x, v[0].y+v[2].y);
    float2 t1=make_float2(v[0].x-v[2].x, v[0].y-v[2].y);
    float2 t2=make_float2(v[1].x+v[3].x, v[1].y+v[3].y);
    float2 t3=make_float2(v[1].x-v[3].x, v[1].y-v[3].y);
    v[0]=make_float2(t0.x+t2.x, t0.y+t2.y);
    v[2]=make_float2(t0.x-t2.x, t0.y-t2.y);
    v[1]=make_float2(t1.x - (float)S*t3.y, t1.y + (float)S*t3.x);
    v[3]=make_float2(t1.x + (float)S*t3.y, t1.y - (float)S*t3.x);
  } else if constexpr (R==8){
    float2 e[4]={v[0],v[2],v[4],v[6]};
    float2 o[4]={v[1],v[3],v[5],v[7]};
    butterfly<4,S>(e);
    butterfly<4,S>(o);
    const float h = 0.70710678118654752440f;
    float2 w1=make_float2(h, (float)S*h);
    float2 w2=make_float2(0.f, (float)S);
    float2 w3=make_float2(-h, (float)S*h);
    float2 o1=cmul(o[1],w1), o2=cmul(o[2],w2), o3=cmul(o[3],w3);
    v[0]=make_float2(e[0].x+o[0].x, e[0].y+o[0].y);
    v[4]=make_float2(e[0].x-o[0].x, e[0].y-o[0].y);
    v[1]=make_float2(e[1].x+o1.x, e[1].y+o1.y);
    v[5]=make_float2(e[1].x-o1.x, e[1].y-o1.y);
    v[2]=make_float2(e[2].x+o2.x, e[2].y+o2.y);
    v[6]=make_float2(e[2].x-o2.x, e[2].y-o2.y);
    v[3]=make_float2(e[3].x+o3.x, e[3].y+o3.y);
    v[7]=make_float2(e[3].x-o3.x, e[3].y-o3.y);
  } else {
    float2 x[R];
    #pragma unroll
    for(int k=0;k<R;k++){
      float2 acc=v[0];
      #pragma unroll
      for(int n=1;n<R;n++){
        const int p=(k*n)%R;
        float ang = (float)S * (TWO_PI/(float)R) * (float)p;
        float sn,cs; __sincosf(ang,&sn,&cs);
        acc.x += v[n].x*cs - v[n].y*sn;
        acc.y += v[n].x*sn + v[n].y*cs;
      }
      x[k]=acc;
    }
    #pragma unroll
    for(int k=0;k<R;k++) v[k]=x[k];
  }
}

// One global Stockham pass (forward only; single complex row).
template<int R,int S>
__global__ void __launch_bounds__(256)
fft_pass(const float2* __restrict__ in, float2* __restrict__ out,
         int N, int Ns){
  const int T = N / R;
  int j = blockIdx.x*blockDim.x + threadIdx.x;
  if (j >= T) return;
  int t = j % Ns;
  float u = (float)t / (float)(Ns*R);
  float ang = (float)S * TWO_PI * u;
  float sn,cs; __sincosf(ang,&sn,&cs);
  float2 w1=make_float2(cs,sn);
  float2 wr=make_float2(1.f,0.f);
  float2 v[R];
  #pragma unroll
  for(int r=0;r<R;r++){
    float2 a = in[j + r*T];
    v[r] = cmul(a, wr);
    wr = cmul(wr, w1);
  }
  butterfly<R,S>(v);
  int d = (j/Ns)*(Ns*R) + t;
  #pragma unroll
  for(int r=0;r<R;r++) out[d + r*Ns] = v[r];
}

// First forward pass: radix-8, Ns=1 (no twiddles). Packs the two real rows
// into one complex signal: z[n] = s0[n] + i*s1[n].
__global__ void __launch_bounds__(256)
fft_c2c8(const float* __restrict__ s, float2* __restrict__ y){
  const int T = LS/8;
  int j = blockIdx.x*blockDim.x + threadIdx.x;
  if (j >= T) return;
  const float* x0 = s;
  const float* x1 = s + LS;
  float2 v[8];
  #pragma unroll
  for(int r=0;r<8;r++) v[r] = make_float2(x0[j + r*T], x1[j + r*T]);
  butterfly<8,-1>(v);
  int d = 8*j;
  #pragma unroll
  for(int r=0;r<8;r++) y[d + r] = v[r];
}

// ---- parallel rowspan: head-max / tail-min of nonzero gw per row ----
__global__ void span_init(int* __restrict__ spanA, int* __restrict__ spanB){
  int j = blockIdx.x*blockDim.x + threadIdx.x;
  if (j < NB){ spanA[j] = 0; spanB[j] = MM; }
}

#define SPAN_SLICE 4096
__global__ void __launch_bounds__(256)
rowspan_par(const float* __restrict__ gw, int* __restrict__ spanA,
            int* __restrict__ spanB){
  const int j  = blockIdx.x;
  const int lo = blockIdx.y * SPAN_SLICE;
  const int end = min(lo + SPAN_SLICE, MM);
  const float* g = gw + (size_t)j*MM;
  const int tid = threadIdx.x;
  int mA = -1, mB = MM;
  for (int m = lo + tid*4; m < end; m += 256*4){
    float4 v = *(const float4*)(g + m);
    #pragma unroll
    for (int t = 0; t < 4; t++){
      float f = ((const float*)&v)[t];
      int m2 = m + t;
      if (f != 0.f){
        if (m2 < 61500){ if (m2 > mA) mA = m2; }
        else           { if (m2 < mB) mB = m2; }
      }
    }
  }
  __shared__ int sA[256], sB[256];
  sA[tid]=mA; sB[tid]=mB; __syncthreads();
  for (int s=128; s>0; s>>=1){
    if (tid<s){ sA[tid]=max(sA[tid],sA[tid+s]); sB[tid]=min(sB[tid],sB[tid+s]); }
    __syncthreads();
  }
  if (tid==0){
    if (sA[0] >= 0) atomicMax(&spanA[j], sA[0]+1);
    if (sB[0] < MM) atomicMin(&spanB[j], sB[0]);
  }
}

// Precompute the 96x96 (padded to [96][QP]) bf16 real-form W matrix.
__global__ void __launch_bounds__(256)
a_prep(unsigned short* __restrict__ A96){
  int i = blockIdx.x*blockDim.x + threadIdx.x;
  if (i >= 96*QP) return;
  int R = i / QP, q = i - R*QP;
  float val = 0.f;
  if (R < 82 && q < 82){
    int k2 = R >> 1, c = R & 1, n2 = q >> 1, cp = q & 1;
    int p = (k2*n2) % 41;
    float ang = (float)p * (TWO_PI/41.f);
    float sn, cs; sincosf(ang, &sn, &cs);
    val = c ? (cp ? cs : sn) : (cp ? -sn : cs);
  }
  A96[i] = f2bf(val);
}

// Precompute inverse-FFT stage twiddles (shared by all 8036 blocks).
__global__ void __launch_bounds__(256)
twid_prep(float2* __restrict__ tbl){
  int i = blockIdx.x*blockDim.x + threadIdx.x;
  if (i >= TBL_N) return;
  int t, r, den;
  if (i < TBL3_OFF)      { int l=i;          t=l/4; r=l%4+1; den=25;   }
  else if (i < TBL4_OFF) { int l=i-TBL3_OFF; t=l/4; r=l%4+1; den=125;  }
  else if (i < TBL5_OFF) { int l=i-TBL4_OFF; t=l/2; r=l%2+1; den=375;  }
  else                   { int l=i-TBL5_OFF; t=l/7; r=l%7+1; den=3000; }
  float ang = TWO_PI * (float)(t*r) / (float)den;
  float sn, cs; sincosf(ang, &sn, &cs);
  tbl[i] = make_float2(cs, sn);
}

// ---- pack_gather: coalesced gather + Hermitian unscramble + 41-comb
// transpose into T[row][n2][i]. T lives in d_out (dead until inv_s2). ----
#define PTILE 1681   // 41*41
__global__ void __launch_bounds__(256)
pack_gather(const float2* __restrict__ ft, const int* __restrict__ idx,
            const float* __restrict__ gw, const int* __restrict__ spanA,
            const int* __restrict__ spanB, float2* __restrict__ T, int row0){
  const int row  = row0 + blockIdx.y;
  const int jrow = row % NB;
  const int b    = row / NB;
  const int spA = spanA[jrow], spB = spanB[jrow];
  const int base = blockIdx.x * PTILE;
  const int end  = min(base + PTILE, MM);
  if (!(base < spA || end > spB)) return;     // tile entirely in zero middle
  __shared__ float2 tile[PTILE];              // 13448 B
  const int cnt = end - base;
  const int*   idxr = idx + (size_t)jrow*MM;
  const float* gwr  = gw  + (size_t)jrow*MM;
  for (int l = threadIdx.x; l < cnt; l += 256){
    int n = base + l;
    float g = gwr[n] * (1.0f/(float)MM);
    int id = idxr[n];
    float2 F1 = ft[id];
    float2 F2 = ft[id ? (LS - id) : 0];
    float2 f;
    if (b == 0) f = make_float2(0.5f*(F1.x + F2.x), 0.5f*(F1.y - F2.y));
    else        f = make_float2(0.5f*(F1.y + F2.y), 0.5f*(F2.x - F1.x));
    tile[l] = make_float2(f.x*g, f.y*g);
  }
  __syncthreads();
  float2* Trow = T + (size_t)blockIdx.y*MM;
  const int bm = base % 41;
  for (int l2 = threadIdx.x; l2 < PTILE; l2 += 256){
    int n2 = l2 / 41, w = l2 - 41*n2;
    int l0 = n2 - bm; if (l0 < 0) l0 += 41;
    int l = l0 + 41*w;
    if (l < cnt){
      int n = base + l;
      if (n < spA || n >= spB){
        int ig = n / 41;
        Trow[(size_t)n2*N2 + ig] = tile[l];
      }
    }
  }
}

// LDS Stockham stage, twiddle-free (Ns==1).
template<int R>
__device__ __forceinline__ void lds_stage1(const float2* src, float2* dst, int tid){
  const int T = N2 / R;
  for (int j = tid; j < T; j += 256){
    float2 v[R];
    #pragma unroll
    for (int r = 0; r < R; r++) v[r] = src[j + r*T];
    butterfly<R,1>(v);
    int d = j*R;
    #pragma unroll
    for (int r = 0; r < R; r++) dst[d + r] = v[r];
  }
}

// LDS Stockham stage with precomputed twiddle table tw[t][r-1].
template<int R, int Ns>
__device__ __forceinline__ void lds_stage_t(const float2* src, float2* dst,
                                            int tid, const float2* tw){
  const int T = N2 / R;
  for (int j = tid; j < T; j += 256){
    int t = j % Ns;
    const float2* w = tw + t*(R-1);
    float2 v[R];
    v[0] = src[j];
    #pragma unroll
    for (int r = 1; r < R; r++) v[r] = cmul(src[j + r*T], w[r-1]);
    butterfly<R,1>(v);
    int d = (j/Ns)*(Ns*R) + t;
    #pragma unroll
    for (int r = 0; r < R; r++) dst[d + r*Ns] = v[r];
  }
}

// Inverse stage 1: packed comb read -> 3000-pt LDS FFT (tables) -> fused
// final stage: radix-8 + final twiddle + bf16 pack + global store.
__global__ void __launch_bounds__(256)
inv_s1(const float2* __restrict__ T, const int* __restrict__ spanA,
       const int* __restrict__ spanB, const float2* __restrict__ tbl,
       unsigned short* __restrict__ Bb, int row0){
  __shared__ float2 u0[N2];       // 24 KB
  __shared__ float2 u1[N2];       // 24 KB
  __shared__ float2 tlds[TBL5_OFF]; // 2.96 KB (stage 2-4 tables)
  const int n2  = blockIdx.x;            // 0..40
  const int jrow = (row0 + blockIdx.y) % NB;
  const int tid = threadIdx.x;
  const int spA = spanA[jrow], spB = spanB[jrow];
  const int n1A = (spA - n2 + 40) / 41;
  const int n1B = (spB - n2 + 40) / 41;
  const float2* Trow = T + (size_t)blockIdx.y*MM + (size_t)n2*N2;
  for (int i = tid; i < N2; i += 256){
    float2 val = make_float2(0.f, 0.f);
    if (i < n1A || i >= n1B) val = Trow[i];
    u0[i] = val;
  }
  for (int i = tid; i < TBL5_OFF; i += 256) tlds[i] = tbl[i];
  __syncthreads();
  lds_stage1<5>(u0, u1, tid);                          __syncthreads();
  lds_stage_t<5,5>  (u1, u0, tid, tlds + TBL2_OFF);    __syncthreads();
  lds_stage_t<5,25> (u0, u1, tid, tlds + TBL3_OFF);    __syncthreads();
  lds_stage_t<3,125>(u1, u0, tid, tlds + TBL4_OFF);    __syncthreads();

  // fused stage 5: R=8, Ns=375, T=375; outputs k1 = j + 375*r
  unsigned short* Brow = Bb + (size_t)blockIdx.y*SROW;
  const float2* tbl5 = tbl + TBL5_OFF;
  const int qr = 2*n2, qi = 2*n2+1;
  float sn, cs;
  __sincosf((float)(n2*375) * (TWO_PI/(float)MM), &sn, &cs);
  const float2 wstep = make_float2(cs, sn);
  for (int j = tid; j < 375; j += 256){
    const float2* w = tbl5 + j*7;
    float2 v[8];
    v[0] = u0[j];
    #pragma unroll
    for (int r = 1; r < 8; r++) v[r] = cmul(u0[j + r*375], w[r-1]);
    butterfly<8,1>(v);
    float ang = (float)(n2*j) * (TWO_PI/(float)MM);   // n2*j <= 14960, exact
    __sincosf(ang, &sn, &cs);
    float2 wf = make_float2(cs, sn);
    #pragma unroll
    for (int r = 0; r < 8; r++){
      float2 o = cmul(v[r], wf);
      int k1 = j + 375*r;
      int kb = k1 >> 4, kl = k1 & 15;
      size_t base = (size_t)kb*(QN*16) + kl;
      Brow[base + qr*16] = f2bf(o.x);
      Brow[base + qi*16] = f2bf(o.y);
      wf = cmul(wf, wstep);
    }
  }
}

// Inverse stage 2 via MFMA: Out[R][k1] = sum_q A96[R][q] * B[q][k1].
__global__ void __launch_bounds__(256)
inv_s2_mfma(const unsigned short* __restrict__ A96,
            const unsigned short* __restrict__ Bb,
            float2* __restrict__ out){
  __shared__ unsigned short Als[96*QP];   // 19968 B
  __shared__ unsigned short Bls[64*QP];   // 13312 B
  const int tid = threadIdx.x;

  {
    const uint4* src = (const uint4*)A96;
    uint4* dst = (uint4*)Als;
    for (int f = tid; f < (96*QP*2)/16; f += 256) dst[f] = src[f];
  }
  {
    const unsigned short* Bt = Bb + (size_t)blockIdx.y*SROW
                                  + (size_t)blockIdx.x*4*(QN*16);
    for (int f = tid; f < 768; f += 256){
      uint4 d = *(const uint4*)(Bt + (size_t)f*8);
      int q   = (f >> 1) % QN;
      int kb  = f / (QN*2);
      int kl0 = (f & 1) * 8;
      if (q >= 82) d = make_uint4(0u,0u,0u,0u);
      const unsigned short* e = (const unsigned short*)&d;
      int rbase = kb*16 + kl0;
      #pragma unroll
      for (int j = 0; j < 8; j++)
        Bls[(rbase + j)*QP + q] = e[j];
    }
  }
  __syncthreads();

  const int w = tid >> 6, l = tid & 63;
  const int g = l >> 4, c = l & 15;

  f32x4 acc[6];
  #pragma unroll
  for (int m = 0; m < 6; m++) acc[m] = (f32x4){0.f,0.f,0.f,0.f};

  short8 b0 = *(const short8*)&Bls[(16*w + c)*QP +  0 + 8*g];
  short8 b1 = *(const short8*)&Bls[(16*w + c)*QP + 32 + 8*g];
  short8 b2 = *(const short8*)&Bls[(16*w + c)*QP + 64 + 8*g];
  #pragma unroll
  for (int m = 0; m < 6; m++){
    short8 a0 = *(const short8*)&Als[(16*m + c)*QP +  0 + 8*g];
    short8 a1 = *(const short8*)&Als[(16*m + c)*QP + 32 + 8*g];
    short8 a2 = *(const short8*)&Als[(16*m + c)*QP + 64 + 8*g];
    acc[m] = __builtin_amdgcn_mfma_f32_16x16x32_bf16(a0, b0, acc[m], 0, 0, 0);
    acc[m] = __builtin_amdgcn_mfma_f32_16x16x32_bf16(a1, b1, acc[m], 0, 0, 0);
    acc[m] = __builtin_amdgcn_mfma_f32_16x16x32_bf16(a2, b2, acc[m], 0, 0, 0);
  }

  float2* orow = out + (size_t)blockIdx.y*MM;
  int k1 = blockIdx.x*64 + 16*w + c;
  if (k1 < N2){
    #pragma unroll
    for (int m = 0; m < 6; m++){
      int R0 = 16*m + 4*g;          // even
      int k2a = R0 >> 1;
      int k2b = k2a + 1;
      if (k2a < 41) orow[(size_t)k2a*N2 + k1] = make_float2(acc[m][0], acc[m][1]);
      if (k2b < 41) orow[(size_t)k2b*N2 + k1] = make_float2(acc[m][2], acc[m][3]);
    }
  }
}

extern "C" void kernel_launch(void* const* d_in, const int* in_sizes, int n_in,
                              void* d_out, int out_size, void* d_ws, size_t ws_size,
                              hipStream_t stream){
  const float* s   = (const float*)d_in[0];
  const int*   idx = (const int*)d_in[1];
  const float* gw  = (const float*)d_in[2];
  float2* out = (float2*)d_out;
  char* ws = (char*)d_ws;

  const size_t FWD_BYTES = 10584064;            // >= LS*8, 256-aligned
  float2* bufA = (float2*)ws;
  float2* bufB = (float2*)(ws + FWD_BYTES);
  int* spanA = (int*)(ws + 2*FWD_BYTES);
  int* spanB = (int*)(ws + 2*FWD_BYTES + 512);
  unsigned short* A96 = (unsigned short*)(ws + 2*FWD_BYTES + 1024);
  const size_t A_BYTES = 20480;                 // >= 96*QP*2
  float2* tbl = (float2*)(ws + 2*FWD_BYTES + 1024 + A_BYTES);
  const size_t TBL_BYTES = 24576;               // >= TBL_N*8
  unsigned short* Bbase = (unsigned short*)(ws + 2*FWD_BYTES + 1024 + A_BYTES + TBL_BYTES);

  // 0) constants: W matrix, twiddle tables, spans
  a_prep<<<(96*QP + 255)/256, 256, 0, stream>>>(A96);
  twid_prep<<<(TBL_N + 255)/256, 256, 0, stream>>>(tbl);
  span_init<<<1, 128, 0, stream>>>(spanA, spanB);
  {
    dim3 g(NB, (MM + SPAN_SLICE - 1)/SPAN_SLICE);   // (98, 31)
    rowspan_par<<<g, 256, 0, stream>>>(gw, spanA, spanB);
  }

  // 1) forward FFT of z = s0 + i*s1 (single complex row):
  //    radix-8 + 8 Stockham passes 7,7,5,5,5,3,3,3
  {
    int blks = (LS/8 + 255)/256;
    fft_c2c8<<<blks,256,0,stream>>>(s, bufA);
  }
  float2* cur = bufA; float2* nxt = bufB;
  int Ns = 8;
  #define FWD(R) do{                                                         \
    int blks = (LS/(R) + 255)/256;                                           \
    fft_pass<R,-1><<<blks,256,0,stream>>>(cur, nxt, LS, Ns);                 \
    Ns *= (R);                                                               \
    { float2* tmp=cur; cur=nxt; nxt=tmp; }                                   \
  }while(0)
  FWD(7); FWD(7); FWD(5); FWD(5); FWD(5); FWD(3); FWD(3); FWD(3);
  #undef FWD
  // 8 swaps -> F back in bufA == cur

  // 2) inverse: pack (Hermitian unscramble, into d_out as scratch)
  //    -> s1 (tables + fused bf16 B) -> s2 (MFMA)
  const size_t row_bytes = (size_t)SROW * 2;    // 577536 B
  size_t used = 2*FWD_BYTES + 1024 + A_BYTES + TBL_BYTES;
  size_t avail = (ws_size > used) ? (ws_size - used) : 0;
  int max_chunk = (int)(avail / row_bytes);
  if (max_chunk > NROWS_T) max_chunk = NROWS_T;
  if (max_chunk < 1) max_chunk = 1;

  const int ptiles = (MM + PTILE - 1)/PTILE;    // 74
  for (int c0 = 0; c0 < NROWS_T; c0 += max_chunk){
    int cr = NROWS_T - c0; if (cr > max_chunk) cr = max_chunk;
    float2* Tchunk = out + (size_t)c0*MM;
    dim3 g0(ptiles, cr);
    pack_gather<<<g0,256,0,stream>>>(cur, idx, gw, spanA, spanB, Tchunk, c0);
    dim3 g1(41, cr);
    inv_s1<<<g1,256,0,stream>>>(Tchunk, spanA, spanB, tbl, Bbase, c0);
    dim3 g2(47, cr);   // 47 * 64 = 3008 >= 3000 k1
    inv_s2_mfma<<<g2,256,0,stream>>>(A96, Bbase, Tchunk);
  }
}

// Round 8
// 478.065 us; speedup vs baseline: 1.1352x; 1.0773x over previous
//
#include <hip/hip_runtime.h>

#define LS 1323000
#define NB 98
#define MM 123000
#define N2 3000            // MM / 41
#define BATCH 2
#define NROWS_T (NB*BATCH)
#define TWO_PI 6.28318530717958647692f

// Bb bf16 layout per row: [kb<188][q<96][kl<16], ushort units
#define KBN 188
#define QN  96
#define SROW (KBN*QN*16)       // 288768 ushorts = 577536 B per row
#define QP  104                // padded q stride in LDS (bank-conflict-free)

// twiddle table layout (float2 units), padded strides for LDS bank spread:
// stage2 (Ns=5,R=5): t<5,  stride 5 -> [P2, P2+25)
// stage3 (Ns=25,R=5): t<25, stride 5 -> [P3, P3+125)
// stage4 (Ns=125,R=3): t<125, stride 3 -> [P4, P4+375)
// stage5 (Ns=375,R=8): t<375, stride 7 (global reads) -> [P5, P5+2625)
#define P2 0
#define P3 25
#define P4 150
#define P5 525
#define TBL_N 3150

#define NT1 512            // inv_s1 block size

typedef __attribute__((ext_vector_type(8))) short short8;
typedef __attribute__((ext_vector_type(4))) float f32x4;

__device__ __forceinline__ float2 cmul(float2 a, float2 b){
  return make_float2(a.x*b.x - a.y*b.y, a.x*b.y + a.y*b.x);
}
__device__ __forceinline__ unsigned short f2bf(float f){
  unsigned int u = __float_as_uint(f);
  unsigned int r = (u + 0x7FFFu + ((u >> 16) & 1u)) >> 16;
  return (unsigned short)r;
}

// Small DFT of size R with sign S (+1 inverse, -1 forward), in-place on v[R].
template<int R,int S>
__device__ __forceinline__ void butterfly(float2* v){
  if constexpr (R==4){
    float2 t0=make_float2(v[0].x+v[2].x, v[0].y+v[2].y);
    float2 t1=make_float2(v[0].x-v[2].x, v[0].y-v[2].y);
    float2 t2=make_float2(v[1].x+v[3].x, v[1].y+v[3].y);
    float2 t3=make_float2(v[1].x-v[3].x, v[1].y-v[3].y);
    v[0]=make_float2(t0.x+t2.x, t0.y+t2.y);
    v[2]=make_float2(t0.x-t2.x, t0.y-t2.y);
    v[1]=make_float2(t1.x - (float)S*t3.y, t1.y + (float)S*t3.x);
    v[3]=make_float2(t1.x + (float)S*t3.y, t1.y - (float)S*t3.x);
  } else if constexpr (R==8){
    float2 e[4]={v[0],v[2],v[4],v[6]};
    float2 o[4]={v[1],v[3],v[5],v[7]};
    butterfly<4,S>(e);
    butterfly<4,S>(o);
    const float h = 0.70710678118654752440f;
    float2 w1=make_float2(h, (float)S*h);
    float2 w2=make_float2(0.f, (float)S);
    float2 w3=make_float2(-h, (float)S*h);
    float2 o1=cmul(o[1],w1), o2=cmul(o[2],w2), o3=cmul(o[3],w3);
    v[0]=make_float2(e[0].x+o[0].x, e[0].y+o[0].y);
    v[4]=make_float2(e[0].x-o[0].x, e[0].y-o[0].y);
    v[1]=make_float2(e[1].x+o1.x, e[1].y+o1.y);
    v[5]=make_float2(e[1].x-o1.x, e[1].y-o1.y);
    v[2]=make_float2(e[2].x+o2.x, e[2].y+o2.y);
    v[6]=make_float2(e[2].x-o2.x, e[2].y-o2.y);
    v[3]=make_float2(e[3].x+o3.x, e[3].y+o3.y);
    v[7]=make_float2(e[3].x-o3.x, e[3].y-o3.y);
  } else if constexpr (R==15){
    // 15 = 3 (inner, over a) x 5 (outer, over b); n = 5a + b, k = m + 3c
    float2 A[5][3];
    #pragma unroll
    for (int b=0;b<5;b++){
      float2 t[3] = { v[b], v[b+5], v[b+10] };
      butterfly<3,S>(t);
      #pragma unroll
      for (int m=0;m<3;m++) A[b][m]=t[m];
    }
    // A[b][m] *= e^{S*2pi i*b*m/15}
    constexpr float CC[5][3] = {
      {1.f, 1.f, 1.f},
      {1.f,  0.91354545764260090f,  0.66913060635885820f},
      {1.f,  0.66913060635885820f, -0.10452846326765346f},
      {1.f,  0.30901699437494745f, -0.80901699437494745f},
      {1.f, -0.10452846326765346f, -0.97814760073380570f}};
    constexpr float SS[5][3] = {
      {0.f, 0.f, 0.f},
      {0.f, 0.40673664307580015f, 0.74314482547739420f},
      {0.f, 0.74314482547739420f, 0.99452189536827330f},
      {0.f, 0.95105651629515350f, 0.58778525229247310f},
      {0.f, 0.99452189536827330f, -0.20791169081775931f}};
    #pragma unroll
    for (int m=0;m<3;m++){
      float2 t5[5];
      #pragma unroll
      for (int b=0;b<5;b++){
        float2 w = make_float2(CC[b][m], (float)S*SS[b][m]);
        t5[b] = cmul(A[b][m], w);
      }
      butterfly<5,S>(t5);
      #pragma unroll
      for (int c=0;c<5;c++) v[m+3*c]=t5[c];
    }
  } else {
    float2 x[R];
    #pragma unroll
    for(int k=0;k<R;k++){
      float2 acc=v[0];
      #pragma unroll
      for(int n=1;n<R;n++){
        const int p=(k*n)%R;
        float ang = (float)S * (TWO_PI/(float)R) * (float)p;
        float sn,cs; __sincosf(ang,&sn,&cs);
        acc.x += v[n].x*cs - v[n].y*sn;
        acc.y += v[n].x*sn + v[n].y*cs;
      }
      x[k]=acc;
    }
    #pragma unroll
    for(int k=0;k<R;k++) v[k]=x[k];
  }
}

// One global Stockham pass (forward only; single complex row).
template<int R,int S>
__global__ void __launch_bounds__(256)
fft_pass(const float2* __restrict__ in, float2* __restrict__ out,
         int N, int Ns){
  const int T = N / R;
  int j = blockIdx.x*blockDim.x + threadIdx.x;
  if (j >= T) return;
  int t = j % Ns;
  float u = (float)t / (float)(Ns*R);
  float ang = (float)S * TWO_PI * u;
  float sn,cs; __sincosf(ang,&sn,&cs);
  float2 w1=make_float2(cs,sn);
  float2 wr=make_float2(1.f,0.f);
  float2 v[R];
  #pragma unroll
  for(int r=0;r<R;r++){
    float2 a = in[j + r*T];
    v[r] = cmul(a, wr);
    wr = cmul(wr, w1);
  }
  butterfly<R,S>(v);
  int d = (j/Ns)*(Ns*R) + t;
  #pragma unroll
  for(int r=0;r<R;r++) out[d + r*Ns] = v[r];
}

// First forward pass: radix-8, Ns=1 (no twiddles). Packs the two real rows
// into one complex signal: z[n] = s0[n] + i*s1[n].
__global__ void __launch_bounds__(256)
fft_c2c8(const float* __restrict__ s, float2* __restrict__ y){
  const int T = LS/8;
  int j = blockIdx.x*blockDim.x + threadIdx.x;
  if (j >= T) return;
  const float* x0 = s;
  const float* x1 = s + LS;
  float2 v[8];
  #pragma unroll
  for(int r=0;r<8;r++) v[r] = make_float2(x0[j + r*T], x1[j + r*T]);
  butterfly<8,-1>(v);
  int d = 8*j;
  #pragma unroll
  for(int r=0;r<8;r++) y[d + r] = v[r];
}

// ---- parallel rowspan: head-max / tail-min of nonzero gw per row ----
__global__ void span_init(int* __restrict__ spanA, int* __restrict__ spanB){
  int j = blockIdx.x*blockDim.x + threadIdx.x;
  if (j < NB){ spanA[j] = 0; spanB[j] = MM; }
}

#define SPAN_SLICE 4096
__global__ void __launch_bounds__(256)
rowspan_par(const float* __restrict__ gw, int* __restrict__ spanA,
            int* __restrict__ spanB){
  const int j  = blockIdx.x;
  const int lo = blockIdx.y * SPAN_SLICE;
  const int end = min(lo + SPAN_SLICE, MM);
  const float* g = gw + (size_t)j*MM;
  const int tid = threadIdx.x;
  int mA = -1, mB = MM;
  for (int m = lo + tid*4; m < end; m += 256*4){
    float4 v = *(const float4*)(g + m);
    #pragma unroll
    for (int t = 0; t < 4; t++){
      float f = ((const float*)&v)[t];
      int m2 = m + t;
      if (f != 0.f){
        if (m2 < 61500){ if (m2 > mA) mA = m2; }
        else           { if (m2 < mB) mB = m2; }
      }
    }
  }
  __shared__ int sA[256], sB[256];
  sA[tid]=mA; sB[tid]=mB; __syncthreads();
  for (int s=128; s>0; s>>=1){
    if (tid<s){ sA[tid]=max(sA[tid],sA[tid+s]); sB[tid]=min(sB[tid],sB[tid+s]); }
    __syncthreads();
  }
  if (tid==0){
    if (sA[0] >= 0) atomicMax(&spanA[j], sA[0]+1);
    if (sB[0] < MM) atomicMin(&spanB[j], sB[0]);
  }
}

// Precompute the 96x96 (padded to [96][QP]) bf16 real-form W matrix.
__global__ void __launch_bounds__(256)
a_prep(unsigned short* __restrict__ A96){
  int i = blockIdx.x*blockDim.x + threadIdx.x;
  if (i >= 96*QP) return;
  int R = i / QP, q = i - R*QP;
  float val = 0.f;
  if (R < 82 && q < 82){
    int k2 = R >> 1, c = R & 1, n2 = q >> 1, cp = q & 1;
    int p = (k2*n2) % 41;
    float ang = (float)p * (TWO_PI/41.f);
    float sn, cs; sincosf(ang, &sn, &cs);
    val = c ? (cp ? cs : sn) : (cp ? -sn : cs);
  }
  A96[i] = f2bf(val);
}

// Precompute inverse-FFT stage twiddles (padded strides; see layout above).
__global__ void __launch_bounds__(256)
twid_prep(float2* __restrict__ tbl){
  int i = blockIdx.x*blockDim.x + threadIdx.x;
  if (i >= TBL_N) return;
  int t=0, r=0, den=1; bool valid=true;
  if (i < P3)      { t=i/5;          int rm=i%5;        valid=(rm<4); r=rm+1; den=25;   }
  else if (i < P4) { int l=i-P3; t=l/5; int rm=l%5;     valid=(rm<4); r=rm+1; den=125;  }
  else if (i < P5) { int l=i-P4; t=l/3; int rm=l%3;     valid=(rm<2); r=rm+1; den=375;  }
  else             { int l=i-P5; t=l/7; r=l%7+1;        den=3000; }
  float2 w = make_float2(1.f, 0.f);
  if (valid){
    float ang = TWO_PI * (float)(t*r) / (float)den;
    float sn, cs; sincosf(ang, &sn, &cs);
    w = make_float2(cs, sn);
  }
  tbl[i] = w;
}

// ---- pack_gather: coalesced gather + Hermitian unscramble + 41-comb
// transpose into T[row][n2][i]. T lives in d_out (dead until inv_s2). ----
#define PTILE 1681   // 41*41
__global__ void __launch_bounds__(256)
pack_gather(const float2* __restrict__ ft, const int* __restrict__ idx,
            const float* __restrict__ gw, const int* __restrict__ spanA,
            const int* __restrict__ spanB, float2* __restrict__ T, int row0){
  const int row  = row0 + blockIdx.y;
  const int jrow = row % NB;
  const int b    = row / NB;
  const int spA = spanA[jrow], spB = spanB[jrow];
  const int base = blockIdx.x * PTILE;
  const int end  = min(base + PTILE, MM);
  if (!(base < spA || end > spB)) return;     // tile entirely in zero middle
  __shared__ float2 tile[PTILE];              // 13448 B
  const int cnt = end - base;
  const int*   idxr = idx + (size_t)jrow*MM;
  const float* gwr  = gw  + (size_t)jrow*MM;
  for (int l = threadIdx.x; l < cnt; l += 256){
    int n = base + l;
    float g = gwr[n] * (1.0f/(float)MM);
    int id = idxr[n];
    float2 F1 = ft[id];
    float2 F2 = ft[id ? (LS - id) : 0];
    float2 f;
    if (b == 0) f = make_float2(0.5f*(F1.x + F2.x), 0.5f*(F1.y - F2.y));
    else        f = make_float2(0.5f*(F1.y + F2.y), 0.5f*(F2.x - F1.x));
    tile[l] = make_float2(f.x*g, f.y*g);
  }
  __syncthreads();
  float2* Trow = T + (size_t)blockIdx.y*MM;
  const int bm = base % 41;
  for (int l2 = threadIdx.x; l2 < PTILE; l2 += 256){
    int n2 = l2 / 41, w = l2 - 41*n2;
    int l0 = n2 - bm; if (l0 < 0) l0 += 41;
    int l = l0 + 41*w;
    if (l < cnt){
      int n = base + l;
      if (n < spA || n >= spB){
        int ig = n / 41;
        Trow[(size_t)n2*N2 + ig] = tile[l];
      }
    }
  }
}

// LDS Stockham stage, twiddle-free (Ns==1).
template<int R, int NT>
__device__ __forceinline__ void lds_stage1(const float2* src, float2* dst, int tid){
  const int T = N2 / R;
  for (int j = tid; j < T; j += NT){
    float2 v[R];
    #pragma unroll
    for (int r = 0; r < R; r++) v[r] = src[j + r*T];
    butterfly<R,1>(v);
    int d = j*R;
    #pragma unroll
    for (int r = 0; r < R; r++) dst[d + r] = v[r];
  }
}

// LDS Stockham stage with precomputed twiddle table tw[t*TS + (r-1)].
template<int R, int Ns, int TS, int NT>
__device__ __forceinline__ void lds_stage_t(const float2* src, float2* dst,
                                            int tid, const float2* tw){
  const int T = N2 / R;
  for (int j = tid; j < T; j += NT){
    int t = j % Ns;
    const float2* w = tw + t*TS;
    float2 v[R];
    v[0] = src[j];
    #pragma unroll
    for (int r = 1; r < R; r++) v[r] = cmul(src[j + r*T], w[r-1]);
    butterfly<R,1>(v);
    int d = (j/Ns)*(Ns*R) + t;
    #pragma unroll
    for (int r = 0; r < R; r++) dst[d + r*Ns] = v[r];
  }
}

// Inverse stage 1: packed comb read -> 3000-pt LDS FFT (tables) -> fused
// final stage: radix-8 + final twiddle + bf16 pack + global store.
__global__ void __launch_bounds__(NT1)
inv_s1(const float2* __restrict__ T, const int* __restrict__ spanA,
       const int* __restrict__ spanB, const float2* __restrict__ tbl,
       unsigned short* __restrict__ Bb, int row0){
  __shared__ float2 u0[N2];       // 24 KB
  __shared__ float2 u1[N2];       // 24 KB
  __shared__ float2 tlds[P5];     // 4.2 KB (stage 2-4 tables, padded)
  const int n2  = blockIdx.x;            // 0..40
  const int jrow = (row0 + blockIdx.y) % NB;
  const int tid = threadIdx.x;
  const int spA = spanA[jrow], spB = spanB[jrow];
  const int n1A = (spA - n2 + 40) / 41;
  const int n1B = (spB - n2 + 40) / 41;
  const float2* Trow = T + (size_t)blockIdx.y*MM + (size_t)n2*N2;
  for (int i = tid; i < N2; i += NT1){
    float2 val = make_float2(0.f, 0.f);
    if (i < n1A || i >= n1B) val = Trow[i];
    u0[i] = val;
  }
  for (int i = tid; i < P5; i += NT1) tlds[i] = tbl[i];
  __syncthreads();
  lds_stage1<5,NT1>(u0, u1, tid);                       __syncthreads();
  lds_stage_t<5,5,5,NT1>  (u1, u0, tid, tlds + P2);     __syncthreads();
  lds_stage_t<5,25,5,NT1> (u0, u1, tid, tlds + P3);     __syncthreads();
  lds_stage_t<3,125,3,NT1>(u1, u0, tid, tlds + P4);     __syncthreads();

  // fused stage 5: R=8, Ns=375, T=375; outputs k1 = j + 375*r
  unsigned short* Brow = Bb + (size_t)blockIdx.y*SROW;
  const float2* tbl5 = tbl + P5;
  const int qr = 2*n2, qi = 2*n2+1;
  float sn, cs;
  __sincosf((float)(n2*375) * (TWO_PI/(float)MM), &sn, &cs);
  const float2 wstep = make_float2(cs, sn);
  for (int j = tid; j < 375; j += NT1){
    const float2* w = tbl5 + j*7;
    float2 v[8];
    v[0] = u0[j];
    #pragma unroll
    for (int r = 1; r < 8; r++) v[r] = cmul(u0[j + r*375], w[r-1]);
    butterfly<8,1>(v);
    float ang = (float)(n2*j) * (TWO_PI/(float)MM);   // n2*j <= 14960, exact
    __sincosf(ang, &sn, &cs);
    float2 wf = make_float2(cs, sn);
    #pragma unroll
    for (int r = 0; r < 8; r++){
      float2 o = cmul(v[r], wf);
      int k1 = j + 375*r;
      int kb = k1 >> 4, kl = k1 & 15;
      size_t base = (size_t)kb*(QN*16) + kl;
      Brow[base + qr*16] = f2bf(o.x);
      Brow[base + qi*16] = f2bf(o.y);
      wf = cmul(wf, wstep);
    }
  }
}

// Inverse stage 2 via MFMA: Out[R][k1] = sum_q A96[R][q] * B[q][k1].
__global__ void __launch_bounds__(256)
inv_s2_mfma(const unsigned short* __restrict__ A96,
            const unsigned short* __restrict__ Bb,
            float2* __restrict__ out){
  __shared__ unsigned short Als[96*QP];   // 19968 B
  __shared__ unsigned short Bls[64*QP];   // 13312 B
  const int tid = threadIdx.x;

  {
    const uint4* src = (const uint4*)A96;
    uint4* dst = (uint4*)Als;
    for (int f = tid; f < (96*QP*2)/16; f += 256) dst[f] = src[f];
  }
  {
    const unsigned short* Bt = Bb + (size_t)blockIdx.y*SROW
                                  + (size_t)blockIdx.x*4*(QN*16);
    for (int f = tid; f < 768; f += 256){
      uint4 d = *(const uint4*)(Bt + (size_t)f*8);
      int q   = (f >> 1) % QN;
      int kb  = f / (QN*2);
      int kl0 = (f & 1) * 8;
      if (q >= 82) d = make_uint4(0u,0u,0u,0u);
      const unsigned short* e = (const unsigned short*)&d;
      int rbase = kb*16 + kl0;
      #pragma unroll
      for (int j = 0; j < 8; j++)
        Bls[(rbase + j)*QP + q] = e[j];
    }
  }
  __syncthreads();

  const int w = tid >> 6, l = tid & 63;
  const int g = l >> 4, c = l & 15;

  f32x4 acc[6];
  #pragma unroll
  for (int m = 0; m < 6; m++) acc[m] = (f32x4){0.f,0.f,0.f,0.f};

  short8 b0 = *(const short8*)&Bls[(16*w + c)*QP +  0 + 8*g];
  short8 b1 = *(const short8*)&Bls[(16*w + c)*QP + 32 + 8*g];
  short8 b2 = *(const short8*)&Bls[(16*w + c)*QP + 64 + 8*g];
  #pragma unroll
  for (int m = 0; m < 6; m++){
    short8 a0 = *(const short8*)&Als[(16*m + c)*QP +  0 + 8*g];
    short8 a1 = *(const short8*)&Als[(16*m + c)*QP + 32 + 8*g];
    short8 a2 = *(const short8*)&Als[(16*m + c)*QP + 64 + 8*g];
    acc[m] = __builtin_amdgcn_mfma_f32_16x16x32_bf16(a0, b0, acc[m], 0, 0, 0);
    acc[m] = __builtin_amdgcn_mfma_f32_16x16x32_bf16(a1, b1, acc[m], 0, 0, 0);
    acc[m] = __builtin_amdgcn_mfma_f32_16x16x32_bf16(a2, b2, acc[m], 0, 0, 0);
  }

  float2* orow = out + (size_t)blockIdx.y*MM;
  int k1 = blockIdx.x*64 + 16*w + c;
  if (k1 < N2){
    #pragma unroll
    for (int m = 0; m < 6; m++){
      int R0 = 16*m + 4*g;          // even
      int k2a = R0 >> 1;
      int k2b = k2a + 1;
      if (k2a < 41) orow[(size_t)k2a*N2 + k1] = make_float2(acc[m][0], acc[m][1]);
      if (k2b < 41) orow[(size_t)k2b*N2 + k1] = make_float2(acc[m][2], acc[m][3]);
    }
  }
}

extern "C" void kernel_launch(void* const* d_in, const int* in_sizes, int n_in,
                              void* d_out, int out_size, void* d_ws, size_t ws_size,
                              hipStream_t stream){
  const float* s   = (const float*)d_in[0];
  const int*   idx = (const int*)d_in[1];
  const float* gw  = (const float*)d_in[2];
  float2* out = (float2*)d_out;
  char* ws = (char*)d_ws;

  const size_t FWD_BYTES = 10584064;            // >= LS*8, 256-aligned
  float2* bufA = (float2*)ws;
  float2* bufB = (float2*)(ws + FWD_BYTES);
  int* spanA = (int*)(ws + 2*FWD_BYTES);
  int* spanB = (int*)(ws + 2*FWD_BYTES + 512);
  unsigned short* A96 = (unsigned short*)(ws + 2*FWD_BYTES + 1024);
  const size_t A_BYTES = 20480;                 // >= 96*QP*2
  float2* tbl = (float2*)(ws + 2*FWD_BYTES + 1024 + A_BYTES);
  const size_t TBL_BYTES = 25600;               // >= TBL_N*8
  unsigned short* Bbase = (unsigned short*)(ws + 2*FWD_BYTES + 1024 + A_BYTES + TBL_BYTES);

  // 0) constants: W matrix, twiddle tables, spans
  a_prep<<<(96*QP + 255)/256, 256, 0, stream>>>(A96);
  twid_prep<<<(TBL_N + 255)/256, 256, 0, stream>>>(tbl);
  span_init<<<1, 128, 0, stream>>>(spanA, spanB);
  {
    dim3 g(NB, (MM + SPAN_SLICE - 1)/SPAN_SLICE);   // (98, 31)
    rowspan_par<<<g, 256, 0, stream>>>(gw, spanA, spanB);
  }

  // 1) forward FFT of z = s0 + i*s1 (single complex row):
  //    radix-8 + 5 Stockham passes 7,7,15,15,15
  {
    int blks = (LS/8 + 255)/256;
    fft_c2c8<<<blks,256,0,stream>>>(s, bufA);
  }
  float2* cur = bufA; float2* nxt = bufB;
  int Ns = 8;
  #define FWD(R) do{                                                         \
    int blks = (LS/(R) + 255)/256;                                           \
    fft_pass<R,-1><<<blks,256,0,stream>>>(cur, nxt, LS, Ns);                 \
    Ns *= (R);                                                               \
    { float2* tmp=cur; cur=nxt; nxt=tmp; }                                   \
  }while(0)
  FWD(7); FWD(7); FWD(15); FWD(15); FWD(15);
  #undef FWD
  // 5 swaps -> F in bufB == cur

  // 2) inverse: pack (Hermitian unscramble, into d_out as scratch)
  //    -> s1 (tables + fused bf16 B) -> s2 (MFMA)
  const size_t row_bytes = (size_t)SROW * 2;    // 577536 B
  size_t used = 2*FWD_BYTES + 1024 + A_BYTES + TBL_BYTES;
  size_t avail = (ws_size > used) ? (ws_size - used) : 0;
  int max_chunk = (int)(avail / row_bytes);
  if (max_chunk > NROWS_T) max_chunk = NROWS_T;
  if (max_chunk < 1) max_chunk = 1;

  const int ptiles = (MM + PTILE - 1)/PTILE;    // 74
  for (int c0 = 0; c0 < NROWS_T; c0 += max_chunk){
    int cr = NROWS_T - c0; if (cr > max_chunk) cr = max_chunk;
    float2* Tchunk = out + (size_t)c0*MM;
    dim3 g0(ptiles, cr);
    pack_gather<<<g0,256,0,stream>>>(cur, idx, gw, spanA, spanB, Tchunk, c0);
    dim3 g1(41, cr);
    inv_s1<<<g1,NT1,0,stream>>>(Tchunk, spanA, spanB, tbl, Bbase, c0);
    dim3 g2(47, cr);   // 47 * 64 = 3008 >= 3000 k1
    inv_s2_mfma<<<g2,256,0,stream>>>(A96, Bbase, Tchunk);
  }
}